// Round 6
// baseline (152.867 us; speedup 1.0000x reference)
//
#include <hip/hip_runtime.h>
#include <stdint.h>

#define T_ 256
#define B_ 8
#define E_ 512
#define H_ 32
#define HD_ 16
#define EXP_ 512
#define S_ 768          // T_ + EXP_
#define M_ 2048         // T_ * B_
#define SMOOTH_ 20.0f
#define PSTR 40         // P-tile LDS row stride (bf16)
#define VSTR 800        // V^T LDS row stride (bf16)
#define OSTR 20         // O-combine LDS row stride (f32)
#define ABST 1024       // Ab row stride in d_out's ushort view (2048B rows)
#define LOG2E_ 1.44269504f
#define MB0_  (-100.988655f)   // -70 * log2e

typedef __attribute__((ext_vector_type(8)))  short bf16x8;
typedef __attribute__((ext_vector_type(4)))  float f32x4;
typedef __attribute__((ext_vector_type(16))) float f32x16;

// round-half-up pack: two fp32 -> dword of two bf16 (lo=a, hi=b)
__device__ __forceinline__ unsigned int pku(float a, float b)
{
    return ((__float_as_uint(a) + 0x8000u) >> 16) |
           ((__float_as_uint(b) + 0x8000u) & 0xFFFF0000u);
}
// single-instruction packed f32->bf16 (RNE), lo = a, hi = b
__device__ __forceinline__ unsigned int cvtpk(float a, float b)
{
    unsigned int r;
    asm("v_cvt_pk_bf16_f32 %0, %1, %2" : "=v"(r) : "v"(a), "v"(b));
    return r;
}
__device__ __forceinline__ ushort bf1(float a)   // RNE
{
    unsigned int u = __float_as_uint(a);
    u = u + 0x7FFFu + ((u >> 16) & 1u);
    return (ushort)(u >> 16);
}

union U16 { uint4 u; bf16x8 v; };

// ---------------------------------------------------------------------------
// Fused QKV-GEMM + attention: R1/v13 structure verbatim (best measured,
// 42.0 us) with (a) Phase-A staging pku -> cvtpk (VALU reduction, proven
// R2-R5) and (b) Ab written into d_out's ushort view at row stride 1024
// (NO workspace use anywhere -> the 256MiB ws re-poison fill may vanish).
// XCD-aware decode b = bid&7 (FETCH 42.7 -> 17.5 MB, R1-verified).
// ---------------------------------------------------------------------------
__global__ __launch_bounds__(1024, 4)
void qkv_attn_kernel(const float* __restrict__ X,
                     const float* __restrict__ Wq, const float* __restrict__ Wk,
                     const float* __restrict__ Wv,
                     const float* __restrict__ bq, const float* __restrict__ bv,
                     const float* __restrict__ LAW,
                     const int* __restrict__ kpm, const int* __restrict__ em,
                     const int* __restrict__ oc, ushort* __restrict__ Ab)
{
    __shared__ __align__(16) char raw[102400];
    ushort* Ks  = (ushort*)(raw);            // 768*16 bf16   = 24576 B
    ushort* Vt  = (ushort*)(raw + 24576);    // 16*VSTR bf16  = 25600 B
    ushort* Qi  = (ushort*)(raw + 50176);    // 256*16 bf16   =  8192 B
    float*  msf = (float*) (raw + 58368);    // 768 f32       =  3072 B
    ushort* Pbb = (ushort*)(raw + 61440);    // 16*32*PSTR    = 40960 B -> 102400
    ushort* As  = (ushort*)(raw);            // phase A alias: 256*72 = 36864 B
    ushort* Bs  = (ushort*)(raw + 36864);    // phase A alias: 48*72  =  6912 B
    float*  Obuf= (float*) (raw);            // post-loop alias: 256*OSTR f32 = 20480 B
    float*  Zb  = (float*) (raw + 58368);    // post-loop alias on msf: 2*256 f32
    ushort* Ob  = Qi;                        // epilogue alias (Qi dead)

    const int bh  = blockIdx.x;
    const int b   = bh & 7;        // XCD-aware: same-b blocks share an XCD L2
    const int h   = bh >> 3;
    const int tid = threadIdx.x;
    const int w   = tid >> 6;      // 0..15
    const int l   = tid & 63;

    // ======================= Phase A: QKV GEMM =======================
    const int r0 = tid >> 3;          // t-row 0..127 (also covers r0+128)
    const int c8 = tid & 7;           // 8-float chunk in the 64-k tile
    const float* Xc0 = &X[((size_t)r0 * 8 + b) * E_ + c8 * 8];
    const float* Xc1 = Xc0 + (size_t)128 * 8 * E_;

    const int wr = tid >> 3;          // valid < 48 (tid < 384)
    const bool wload = (tid < 384);   // wave-uniform (waves 0..5)
    const float* Wsel = (wr < 16) ? Wq : (wr < 32 ? Wk : Wv);
    const float* Wr = &Wsel[((size_t)(h * 16 + (wr & 15))) * E_ + c8 * 8];
    ushort* Bxw = &Bs[wr * 72 + c8 * 8];

    f32x4 acc[3];
#pragma unroll
    for (int m = 0; m < 3; ++m) acc[m] = (f32x4){0.f, 0.f, 0.f, 0.f};

    float4 xa0, xa1, xb0, xb1, wp0, wp1;
    xa0 = *(const float4*)&Xc0[0]; xa1 = *(const float4*)&Xc0[4];
    xb0 = *(const float4*)&Xc1[0]; xb1 = *(const float4*)&Xc1[4];
    if (wload) { wp0 = *(const float4*)&Wr[0]; wp1 = *(const float4*)&Wr[4]; }

    const int ln = l & 15;
    const int lg = l >> 4;

    for (int it = 0; it < 8; ++it) {
        __syncthreads();
        *(uint4*)&As[r0 * 72 + c8 * 8] =
            make_uint4(cvtpk(xa0.x, xa0.y), cvtpk(xa0.z, xa0.w),
                       cvtpk(xa1.x, xa1.y), cvtpk(xa1.z, xa1.w));
        *(uint4*)&As[(r0 + 128) * 72 + c8 * 8] =
            make_uint4(cvtpk(xb0.x, xb0.y), cvtpk(xb0.z, xb0.w),
                       cvtpk(xb1.x, xb1.y), cvtpk(xb1.z, xb1.w));
        if (wload)
            *(uint4*)&Bxw[0] = make_uint4(cvtpk(wp0.x, wp0.y), cvtpk(wp0.z, wp0.w),
                                          cvtpk(wp1.x, wp1.y), cvtpk(wp1.z, wp1.w));
        __syncthreads();
        if (it < 7) {
            Xc0 += 64; Xc1 += 64;
            xa0 = *(const float4*)&Xc0[0]; xa1 = *(const float4*)&Xc0[4];
            xb0 = *(const float4*)&Xc1[0]; xb1 = *(const float4*)&Xc1[4];
            if (wload) { Wr += 64; wp0 = *(const float4*)&Wr[0]; wp1 = *(const float4*)&Wr[4]; }
        }
#pragma unroll
        for (int kb = 0; kb < 2; ++kb) {
            bf16x8 af = *(const bf16x8*)&As[(w * 16 + ln) * 72 + kb * 32 + lg * 8];
#pragma unroll
            for (int m = 0; m < 3; ++m) {
                bf16x8 bfm = *(const bf16x8*)&Bs[(m * 16 + ln) * 72 + kb * 32 + lg * 8];
                acc[m] = __builtin_amdgcn_mfma_f32_16x16x32_bf16(af, bfm, acc[m], 0, 0, 0);
            }
        }
    }

    __syncthreads();   // As/Bs dead; image region may be written

    // ---- write Q/K/V images (C-layout: col=ln=d, row=lg*4+r) ----
    {
        const float bqv = bq[h * 16 + ln];
        const float bvv = bv[h * 16 + ln];
#pragma unroll
        for (int r = 0; r < 4; ++r) {
            const int t = w * 16 + lg * 4 + r;
            Qi[t * 16 + ln]   = bf1(acc[0][r] + bqv);
            Ks[t * 16 + ln]   = bf1(acc[1][r]);
            Vt[ln * VSTR + t] = bf1(acc[2][r] + bvv);
        }
    }
    __syncthreads();

    // ---- expansion rows/cols 256..767 (LDS->LDS) + masks ----
    if (tid < 512) {
        const int j   = tid;
        const int src = oc[b * EXP_ + j];
        uint4 k0 = *(const uint4*)&Ks[src * 16];
        uint4 k1 = *(const uint4*)&Ks[src * 16 + 8];
        *(uint4*)&Ks[(T_ + j) * 16]     = k0;
        *(uint4*)&Ks[(T_ + j) * 16 + 8] = k1;
    } else {
        const int j   = tid - 512;
        const int src = oc[b * EXP_ + j];
#pragma unroll
        for (int d = 0; d < 16; ++d)
            Vt[d * VSTR + T_ + j] = Vt[d * VSTR + src];
    }
    if (tid < 768) {
        const int s = tid;
        const int m = (s < T_) ? kpm[b * T_ + s] : em[b * EXP_ + (s - T_)];
        msf[s] = m ? -1.0e5f : MB0_;
    }
    __syncthreads();

    // ======================= Phase B: attention =======================
    const int slane = l & 31;
    const int khalf = l >> 5;
    const int tl = l & 15;
    const int kg = l >> 4;
    const int tq = w & 7;          // t32-tile
    const int sh = w >> 3;         // s-half

    bf16x8 qf = *(const bf16x8*)&Qi[(tq * 32 + slane) * 16 + khalf * 8];

    const f32x16 zero16 = {0.f,0.f,0.f,0.f,0.f,0.f,0.f,0.f,
                           0.f,0.f,0.f,0.f,0.f,0.f,0.f,0.f};
    f32x4 o0 = {0.f, 0.f, 0.f, 0.f};
    f32x4 o1 = {0.f, 0.f, 0.f, 0.f};
    float zacc[16];
#pragma unroll
    for (int r = 0; r < 16; ++r) zacc[r] = 0.f;

    const float* lawb = &LAW[((size_t)b * T_ + tq * 32 + khalf * 4) * S_ + slane];
    ushort* pw = &Pbb[w * 32 * PSTR + slane];
    ushort* pt = &Pbb[w * 32 * PSTR];

    for (int i = sh * 12; i < sh * 12 + 12; ++i) {
        bf16x8 kf = *(const bf16x8*)&Ks[(i * 32 + slane) * 16 + khalf * 8];

        float lw[16];
        const float* lp = lawb + i * 32;
#pragma unroll
        for (int r = 0; r < 16; ++r)
            lw[r] = lp[(size_t)((r & 3) + 8 * (r >> 2)) * S_];

        f32x16 sc = __builtin_amdgcn_mfma_f32_32x32x16_bf16(qf, kf, zero16, 0, 0, 0);
        const float mb = msf[i * 32 + slane];

#pragma unroll
        for (int r = 0; r < 16; ++r) {
            const float lwK = lw[r] * LOG2E_;
            const float arg = __builtin_fmaf(sc[r], lwK,
                              __builtin_fmaf(lwK, SMOOTH_, mb));
            const float e = __builtin_amdgcn_exp2f(arg);
            zacc[r] += e;
            const float p = e * lw[r];
            pw[((r & 3) + 8 * (r >> 2) + 4 * khalf) * PSTR] =
                (ushort)((__float_as_uint(p) + 0x8000u) >> 16);
        }

        bf16x8 vf = *(const bf16x8*)&Vt[tl * VSTR + i * 32 + kg * 8];
        {
            const ushort* pr0 = &pt[(0 * 16 + tl) * PSTR + kg * 8];
            U16 u;
            uint2 a0 = *(const uint2*)pr0;
            uint2 a1 = *(const uint2*)(pr0 + 4);
            u.u = make_uint4(a0.x, a0.y, a1.x, a1.y);
            o0 = __builtin_amdgcn_mfma_f32_16x16x32_bf16(vf, u.v, o0, 0, 0, 0);
            const ushort* pr1 = &pt[(1 * 16 + tl) * PSTR + kg * 8];
            uint2 b0 = *(const uint2*)pr1;
            uint2 b1 = *(const uint2*)(pr1 + 4);
            u.u = make_uint4(b0.x, b0.y, b1.x, b1.y);
            o1 = __builtin_amdgcn_mfma_f32_16x16x32_bf16(vf, u.v, o1, 0, 0, 0);
        }
    }

    // reduce zacc across the 32-lane s-groups (khalf halves independent)
#pragma unroll
    for (int m = 1; m < 32; m <<= 1) {
#pragma unroll
        for (int r = 0; r < 16; ++r)
            zacc[r] += __shfl_xor(zacc[r], m);
    }

    __syncthreads();   // all waves past the loop: Ks/msf dead, alias safe

    if (l == 0 || l == 32) {
#pragma unroll
        for (int r = 0; r < 16; ++r)
            Zb[sh * 256 + tq * 32 + (r & 3) + 8 * (r >> 2) + 4 * khalf] = zacc[r];
    }
    if (sh == 1) {
#pragma unroll
        for (int th = 0; th < 2; ++th) {
            const f32x4 o = th ? o1 : o0;
            *(float4*)&Obuf[((size_t)(tq * 32 + th * 16 + tl)) * OSTR + kg * 4] =
                make_float4(o[0], o[1], o[2], o[3]);
        }
    }
    __syncthreads();

    if (sh == 0) {
#pragma unroll
        for (int th = 0; th < 2; ++th) {
            const int t = tq * 32 + th * 16 + tl;
            const float Zt  = Zb[t] + Zb[256 + t];
            const float inv = (Zt > 0.f) ? 1.f / Zt : 0.f;
            float4 po = *(const float4*)&Obuf[(size_t)t * OSTR + kg * 4];
            const f32x4 o = th ? o1 : o0;
            float ov[4] = {(o[0] + po.x) * inv, (o[1] + po.y) * inv,
                           (o[2] + po.z) * inv, (o[3] + po.w) * inv};
            *(uint*)&Ob[t * 16 + kg * 4]     = pku(ov[0], ov[1]);
            *(uint*)&Ob[t * 16 + kg * 4 + 2] = pku(ov[2], ov[3]);
        }
    }
    __syncthreads();

    // store Ab into d_out's ushort view: row m = t*8+b (stride 1024),
    // cols h*16..h*16+16 (Ab occupies float cols 0..255 of each out row)
    {
        const int t  = tid >> 2;
        const int q4 = tid & 3;
        *(uint2*)&Ab[((size_t)(t * 8 + b)) * ABST + h * 16 + q4 * 4] =
            *(const uint2*)&Ob[t * 16 + q4 * 4];
    }
}

// ---------------------------------------------------------------------------
// out GEMM v5, IN-PLACE on d_out (no workspace): m-only tiling, 64 blocks x
// 512 threads (8 waves), 32 rows/block, full N=512 per block. Each block
// loads its ENTIRE A panel (32x512 bf16, from dst's ushort view) into LDS
// BEFORE writing any output to those rows -> in-place is race-free (no
// n-split => no cross-block hazard). B = Wo fp32 staged 64n x 128k per step.
// ---------------------------------------------------------------------------
__global__ __launch_bounds__(512, 2)
void out_gemm(const float* __restrict__ Wo, const float* __restrict__ bo,
              float* __restrict__ dst)
{
    __shared__ __align__(16) ushort As[32 * 520];   // 33280 B (stride 520: 2-way banks)
    __shared__ __align__(16) ushort Bs[64 * 136];   // 17408 B

    const int m0  = blockIdx.x * 32;
    const int tid = threadIdx.x;          // 0..511
    const int l   = tid & 63;
    const int w   = tid >> 6;             // 0..7
    const int wm  = w & 1;                // 16-row m half
    const int wn  = w >> 1;               // 16-col n quarter (of 64-tile)
    const int lq  = l >> 4;
    const int ln  = l & 15;

    // ---- load A panel (32 rows x 512 k bf16) from dst's ushort view ----
    {
        const ushort* Abp = (const ushort*)dst;
        const int r = tid >> 4;           // 0..31
        const int c = (tid & 15) * 32;    // 0..480
        const ushort* sp = &Abp[(size_t)(m0 + r) * ABST + c];
        uint4 a0 = *(const uint4*)(sp);
        uint4 a1 = *(const uint4*)(sp + 8);
        uint4 a2 = *(const uint4*)(sp + 16);
        uint4 a3 = *(const uint4*)(sp + 24);
        ushort* dp = &As[r * 520 + c];
        *(uint4*)(dp)      = a0;
        *(uint4*)(dp + 8)  = a1;
        *(uint4*)(dp + 16) = a2;
        *(uint4*)(dp + 24) = a3;
    }

    // per-n-tile bias for this lane's output column
    float bov[8];
#pragma unroll
    for (int nt = 0; nt < 8; ++nt)
        bov[nt] = bo[nt * 64 + wn * 16 + ln];

    const int brow = tid >> 3;            // 0..63 (n within tile)
    const int bcol = (tid & 7) * 16;      // 0..112 (k within 128-chunk)

    // prefetch stage 0: nt=0, kt=0
    const float* Wp = &Wo[(size_t)brow * E_ + bcol];
    float4 f0 = *(const float4*)&Wp[0];
    float4 f1 = *(const float4*)&Wp[4];
    float4 f2 = *(const float4*)&Wp[8];
    float4 f3 = *(const float4*)&Wp[12];

    f32x4 acc = {0.f, 0.f, 0.f, 0.f};

    for (int s = 0; s < 32; ++s) {        // s = nt*4 + kt
        __syncthreads();                  // prev compute done (s=0: A panel done)
        *(uint4*)&Bs[brow * 136 + bcol] =
            make_uint4(cvtpk(f0.x, f0.y), cvtpk(f0.z, f0.w),
                       cvtpk(f1.x, f1.y), cvtpk(f1.z, f1.w));
        *(uint4*)&Bs[brow * 136 + bcol + 8] =
            make_uint4(cvtpk(f2.x, f2.y), cvtpk(f2.z, f2.w),
                       cvtpk(f3.x, f3.y), cvtpk(f3.z, f3.w));
        __syncthreads();                  // Bs ready
        if (s < 31) {
            const int sn = s + 1;
            const float* Wn = &Wo[(size_t)((sn >> 2) * 64 + brow) * E_ +
                                  (sn & 3) * 128 + bcol];
            f0 = *(const float4*)&Wn[0];
            f1 = *(const float4*)&Wn[4];
            f2 = *(const float4*)&Wn[8];
            f3 = *(const float4*)&Wn[12];
        }
        const int kt = s & 3;
#pragma unroll
        for (int kb = 0; kb < 4; ++kb) {
            bf16x8 af = *(const bf16x8*)&As[(wm * 16 + ln) * 520 +
                                            kt * 128 + kb * 32 + lq * 8];
            bf16x8 bf = *(const bf16x8*)&Bs[(wn * 16 + ln) * 136 +
                                            kb * 32 + lq * 8];
            acc = __builtin_amdgcn_mfma_f32_16x16x32_bf16(af, bf, acc, 0, 0, 0);
        }
        if (kt == 3) {                    // n-tile complete: write + reset
            const int nt = s >> 2;
            const int gn = nt * 64 + wn * 16 + ln;
            const float bb = bov[nt];
#pragma unroll
            for (int r = 0; r < 4; ++r)
                dst[(size_t)(m0 + wm * 16 + lq * 4 + r) * E_ + gn] = acc[r] + bb;
            acc = (f32x4){0.f, 0.f, 0.f, 0.f};
        }
    }
}

// ---------------------------------------------------------------------------
extern "C" void kernel_launch(void* const* d_in, const int* in_sizes, int n_in,
                              void* d_out, int out_size, void* d_ws, size_t ws_size,
                              hipStream_t stream)
{
    const float* query = (const float*)d_in[0];
    const int*   oc    = (const int*)d_in[1];
    const int*   em    = (const int*)d_in[2];
    const int*   kpm   = (const int*)d_in[3];
    const float* law   = (const float*)d_in[4];
    const float* Wq    = (const float*)d_in[5];
    const float* bq    = (const float*)d_in[6];
    const float* Wk    = (const float*)d_in[7];
    const float* Wv    = (const float*)d_in[8];
    const float* bv    = (const float*)d_in[9];
    const float* Wo    = (const float*)d_in[10];
    const float* bo    = (const float*)d_in[11];
    float* out = (float*)d_out;

    // NO workspace use: Ab lives inside d_out (bf16, row stride 1024 ushorts,
    // occupying float cols 0..255 of each row; overwritten in-place by
    // out_gemm after each block stages its A panel in LDS).
    (void)d_ws; (void)ws_size;
    ushort* Ab = (ushort*)d_out;

    qkv_attn_kernel<<<B_ * H_, 1024, 0, stream>>>(query, Wq, Wk, Wv, bq, bv,
                                                  law, kpm, em, oc, Ab);

    out_gemm<<<M_ / 32, 512, 0, stream>>>(Wo, bo, out);
}

// Round 7
// 124.941 us; speedup vs baseline: 1.2235x; 1.2235x over previous
//
#include <hip/hip_runtime.h>
#include <stdint.h>

#define T_ 256
#define B_ 8
#define E_ 512
#define H_ 32
#define HD_ 16
#define EXP_ 512
#define S_ 768          // T_ + EXP_
#define M_ 2048         // T_ * B_
#define SMOOTH_ 20.0f
#define PSTR 40         // P-tile LDS row stride (bf16)
#define VSTR 800        // V^T LDS row stride (bf16)
#define OSTR 20         // O-combine LDS row stride (f32)
#define LOG2E_ 1.44269504f
#define MB0_  (-100.988655f)   // -70 * log2e

typedef __attribute__((ext_vector_type(8)))  short bf16x8;
typedef __attribute__((ext_vector_type(4)))  float f32x4;
typedef __attribute__((ext_vector_type(16))) float f32x16;

// round-half-up pack: two fp32 -> dword of two bf16 (lo=a, hi=b)
__device__ __forceinline__ unsigned int pku(float a, float b)
{
    return ((__float_as_uint(a) + 0x8000u) >> 16) |
           ((__float_as_uint(b) + 0x8000u) & 0xFFFF0000u);
}
// single-instruction packed f32->bf16 (RNE), lo = a, hi = b
__device__ __forceinline__ unsigned int cvtpk(float a, float b)
{
    unsigned int r;
    asm("v_cvt_pk_bf16_f32 %0, %1, %2" : "=v"(r) : "v"(a), "v"(b));
    return r;
}
__device__ __forceinline__ ushort bf1(float a)   // RNE
{
    unsigned int u = __float_as_uint(a);
    u = u + 0x7FFFu + ((u >> 16) & 1u);
    return (ushort)(u >> 16);
}

union U16 { uint4 u; bf16x8 v; };

// ---------------------------------------------------------------------------
// Fused QKV-GEMM + attention: R1/v13 structure (session-best: 42.0us kernel,
// 125.15 total; R0 variant 124.2) with cvtpk staging (R6-verified neutral).
// Ab goes to d_ws (R6 proved d_out reads are ~8x slower: 43.9us @1% util).
// XCD-aware decode b = bid&7 (FETCH 42.7 -> 17.5 MB, R1-verified).
// ---------------------------------------------------------------------------
__global__ __launch_bounds__(1024, 4)
void qkv_attn_kernel(const float* __restrict__ X,
                     const float* __restrict__ Wq, const float* __restrict__ Wk,
                     const float* __restrict__ Wv,
                     const float* __restrict__ bq, const float* __restrict__ bv,
                     const float* __restrict__ LAW,
                     const int* __restrict__ kpm, const int* __restrict__ em,
                     const int* __restrict__ oc, ushort* __restrict__ Ab)
{
    __shared__ __align__(16) char raw[102400];
    ushort* Ks  = (ushort*)(raw);            // 768*16 bf16   = 24576 B
    ushort* Vt  = (ushort*)(raw + 24576);    // 16*VSTR bf16  = 25600 B
    ushort* Qi  = (ushort*)(raw + 50176);    // 256*16 bf16   =  8192 B
    float*  msf = (float*) (raw + 58368);    // 768 f32       =  3072 B
    ushort* Pbb = (ushort*)(raw + 61440);    // 16*32*PSTR    = 40960 B -> 102400
    ushort* As  = (ushort*)(raw);            // phase A alias: 256*72 = 36864 B
    ushort* Bs  = (ushort*)(raw + 36864);    // phase A alias: 48*72  =  6912 B
    float*  Obuf= (float*) (raw);            // post-loop alias: 256*OSTR f32 = 20480 B
    float*  Zb  = (float*) (raw + 58368);    // post-loop alias on msf: 2*256 f32
    ushort* Ob  = Qi;                        // epilogue alias (Qi dead)

    const int bh  = blockIdx.x;
    const int b   = bh & 7;        // XCD-aware: same-b blocks share an XCD L2
    const int h   = bh >> 3;
    const int tid = threadIdx.x;
    const int w   = tid >> 6;      // 0..15
    const int l   = tid & 63;

    // ======================= Phase A: QKV GEMM =======================
    const int r0 = tid >> 3;          // t-row 0..127 (also covers r0+128)
    const int c8 = tid & 7;           // 8-float chunk in the 64-k tile
    const float* Xc0 = &X[((size_t)r0 * 8 + b) * E_ + c8 * 8];
    const float* Xc1 = Xc0 + (size_t)128 * 8 * E_;

    const int wr = tid >> 3;          // valid < 48 (tid < 384)
    const bool wload = (tid < 384);   // wave-uniform (waves 0..5)
    const float* Wsel = (wr < 16) ? Wq : (wr < 32 ? Wk : Wv);
    const float* Wr = &Wsel[((size_t)(h * 16 + (wr & 15))) * E_ + c8 * 8];
    ushort* Bxw = &Bs[wr * 72 + c8 * 8];

    f32x4 acc[3];
#pragma unroll
    for (int m = 0; m < 3; ++m) acc[m] = (f32x4){0.f, 0.f, 0.f, 0.f};

    float4 xa0, xa1, xb0, xb1, wp0, wp1;
    xa0 = *(const float4*)&Xc0[0]; xa1 = *(const float4*)&Xc0[4];
    xb0 = *(const float4*)&Xc1[0]; xb1 = *(const float4*)&Xc1[4];
    if (wload) { wp0 = *(const float4*)&Wr[0]; wp1 = *(const float4*)&Wr[4]; }

    const int ln = l & 15;
    const int lg = l >> 4;

    for (int it = 0; it < 8; ++it) {
        __syncthreads();
        *(uint4*)&As[r0 * 72 + c8 * 8] =
            make_uint4(cvtpk(xa0.x, xa0.y), cvtpk(xa0.z, xa0.w),
                       cvtpk(xa1.x, xa1.y), cvtpk(xa1.z, xa1.w));
        *(uint4*)&As[(r0 + 128) * 72 + c8 * 8] =
            make_uint4(cvtpk(xb0.x, xb0.y), cvtpk(xb0.z, xb0.w),
                       cvtpk(xb1.x, xb1.y), cvtpk(xb1.z, xb1.w));
        if (wload)
            *(uint4*)&Bxw[0] = make_uint4(cvtpk(wp0.x, wp0.y), cvtpk(wp0.z, wp0.w),
                                          cvtpk(wp1.x, wp1.y), cvtpk(wp1.z, wp1.w));
        __syncthreads();
        if (it < 7) {
            Xc0 += 64; Xc1 += 64;
            xa0 = *(const float4*)&Xc0[0]; xa1 = *(const float4*)&Xc0[4];
            xb0 = *(const float4*)&Xc1[0]; xb1 = *(const float4*)&Xc1[4];
            if (wload) { Wr += 64; wp0 = *(const float4*)&Wr[0]; wp1 = *(const float4*)&Wr[4]; }
        }
#pragma unroll
        for (int kb = 0; kb < 2; ++kb) {
            bf16x8 af = *(const bf16x8*)&As[(w * 16 + ln) * 72 + kb * 32 + lg * 8];
#pragma unroll
            for (int m = 0; m < 3; ++m) {
                bf16x8 bfm = *(const bf16x8*)&Bs[(m * 16 + ln) * 72 + kb * 32 + lg * 8];
                acc[m] = __builtin_amdgcn_mfma_f32_16x16x32_bf16(af, bfm, acc[m], 0, 0, 0);
            }
        }
    }

    __syncthreads();   // As/Bs dead; image region may be written

    // ---- write Q/K/V images (C-layout: col=ln=d, row=lg*4+r) ----
    {
        const float bqv = bq[h * 16 + ln];
        const float bvv = bv[h * 16 + ln];
#pragma unroll
        for (int r = 0; r < 4; ++r) {
            const int t = w * 16 + lg * 4 + r;
            Qi[t * 16 + ln]   = bf1(acc[0][r] + bqv);
            Ks[t * 16 + ln]   = bf1(acc[1][r]);
            Vt[ln * VSTR + t] = bf1(acc[2][r] + bvv);
        }
    }
    __syncthreads();

    // ---- expansion rows/cols 256..767 (LDS->LDS) + masks ----
    if (tid < 512) {
        const int j   = tid;
        const int src = oc[b * EXP_ + j];
        uint4 k0 = *(const uint4*)&Ks[src * 16];
        uint4 k1 = *(const uint4*)&Ks[src * 16 + 8];
        *(uint4*)&Ks[(T_ + j) * 16]     = k0;
        *(uint4*)&Ks[(T_ + j) * 16 + 8] = k1;
    } else {
        const int j   = tid - 512;
        const int src = oc[b * EXP_ + j];
#pragma unroll
        for (int d = 0; d < 16; ++d)
            Vt[d * VSTR + T_ + j] = Vt[d * VSTR + src];
    }
    if (tid < 768) {
        const int s = tid;
        const int m = (s < T_) ? kpm[b * T_ + s] : em[b * EXP_ + (s - T_)];
        msf[s] = m ? -1.0e5f : MB0_;
    }
    __syncthreads();

    // ======================= Phase B: attention =======================
    const int slane = l & 31;
    const int khalf = l >> 5;
    const int tl = l & 15;
    const int kg = l >> 4;
    const int tq = w & 7;          // t32-tile
    const int sh = w >> 3;         // s-half

    bf16x8 qf = *(const bf16x8*)&Qi[(tq * 32 + slane) * 16 + khalf * 8];

    const f32x16 zero16 = {0.f,0.f,0.f,0.f,0.f,0.f,0.f,0.f,
                           0.f,0.f,0.f,0.f,0.f,0.f,0.f,0.f};
    f32x4 o0 = {0.f, 0.f, 0.f, 0.f};
    f32x4 o1 = {0.f, 0.f, 0.f, 0.f};
    float zacc[16];
#pragma unroll
    for (int r = 0; r < 16; ++r) zacc[r] = 0.f;

    const float* lawb = &LAW[((size_t)b * T_ + tq * 32 + khalf * 4) * S_ + slane];
    ushort* pw = &Pbb[w * 32 * PSTR + slane];
    ushort* pt = &Pbb[w * 32 * PSTR];

    for (int i = sh * 12; i < sh * 12 + 12; ++i) {
        bf16x8 kf = *(const bf16x8*)&Ks[(i * 32 + slane) * 16 + khalf * 8];

        float lw[16];
        const float* lp = lawb + i * 32;
#pragma unroll
        for (int r = 0; r < 16; ++r)
            lw[r] = lp[(size_t)((r & 3) + 8 * (r >> 2)) * S_];

        f32x16 sc = __builtin_amdgcn_mfma_f32_32x32x16_bf16(qf, kf, zero16, 0, 0, 0);
        const float mb = msf[i * 32 + slane];

#pragma unroll
        for (int r = 0; r < 16; ++r) {
            const float lwK = lw[r] * LOG2E_;
            const float arg = __builtin_fmaf(sc[r], lwK,
                              __builtin_fmaf(lwK, SMOOTH_, mb));
            const float e = __builtin_amdgcn_exp2f(arg);
            zacc[r] += e;
            const float p = e * lw[r];
            pw[((r & 3) + 8 * (r >> 2) + 4 * khalf) * PSTR] =
                (ushort)((__float_as_uint(p) + 0x8000u) >> 16);
        }

        bf16x8 vf = *(const bf16x8*)&Vt[tl * VSTR + i * 32 + kg * 8];
        {
            const ushort* pr0 = &pt[(0 * 16 + tl) * PSTR + kg * 8];
            U16 u;
            uint2 a0 = *(const uint2*)pr0;
            uint2 a1 = *(const uint2*)(pr0 + 4);
            u.u = make_uint4(a0.x, a0.y, a1.x, a1.y);
            o0 = __builtin_amdgcn_mfma_f32_16x16x32_bf16(vf, u.v, o0, 0, 0, 0);
            const ushort* pr1 = &pt[(1 * 16 + tl) * PSTR + kg * 8];
            uint2 b0 = *(const uint2*)pr1;
            uint2 b1 = *(const uint2*)(pr1 + 4);
            u.u = make_uint4(b0.x, b0.y, b1.x, b1.y);
            o1 = __builtin_amdgcn_mfma_f32_16x16x32_bf16(vf, u.v, o1, 0, 0, 0);
        }
    }

    // reduce zacc across the 32-lane s-groups (khalf halves independent)
#pragma unroll
    for (int m = 1; m < 32; m <<= 1) {
#pragma unroll
        for (int r = 0; r < 16; ++r)
            zacc[r] += __shfl_xor(zacc[r], m);
    }

    __syncthreads();   // all waves past the loop: Ks/msf dead, alias safe

    if (l == 0 || l == 32) {
#pragma unroll
        for (int r = 0; r < 16; ++r)
            Zb[sh * 256 + tq * 32 + (r & 3) + 8 * (r >> 2) + 4 * khalf] = zacc[r];
    }
    if (sh == 1) {
#pragma unroll
        for (int th = 0; th < 2; ++th) {
            const f32x4 o = th ? o1 : o0;
            *(float4*)&Obuf[((size_t)(tq * 32 + th * 16 + tl)) * OSTR + kg * 4] =
                make_float4(o[0], o[1], o[2], o[3]);
        }
    }
    __syncthreads();

    if (sh == 0) {
#pragma unroll
        for (int th = 0; th < 2; ++th) {
            const int t = tq * 32 + th * 16 + tl;
            const float Zt  = Zb[t] + Zb[256 + t];
            const float inv = (Zt > 0.f) ? 1.f / Zt : 0.f;
            float4 po = *(const float4*)&Obuf[(size_t)t * OSTR + kg * 4];
            const f32x4 o = th ? o1 : o0;
            float ov[4] = {(o[0] + po.x) * inv, (o[1] + po.y) * inv,
                           (o[2] + po.z) * inv, (o[3] + po.w) * inv};
            *(uint*)&Ob[t * 16 + kg * 4]     = pku(ov[0], ov[1]);
            *(uint*)&Ob[t * 16 + kg * 4 + 2] = pku(ov[2], ov[3]);
        }
    }
    __syncthreads();

    // store to Ab row-major [m][E]: m = t*8+b, cols h*16..h*16+16
    {
        const int t  = tid >> 2;
        const int q4 = tid & 3;
        *(uint2*)&Ab[((size_t)(t * 8 + b)) * E_ + h * 16 + q4 * 4] =
            *(const uint2*)&Ob[t * 16 + q4 * 4];
    }
}

// ---------------------------------------------------------------------------
// out GEMM (R1-verified v2): 32x64 tiles, 512 blocks -> 2 blocks/CU,
// BK=128 -> 4 K-iters, cvtpk staging. A = Ab bf16 [M][E] in d_ws, B = Wo.
// ---------------------------------------------------------------------------
__global__ __launch_bounds__(256, 2)
void out_gemm(const ushort* __restrict__ Ab, const float* __restrict__ Wo,
              const float* __restrict__ bo, float* __restrict__ dst)
{
    __shared__ __align__(16) ushort sbuf[96 * 136];   // 26112 B
    ushort* As = sbuf;              // 32 rows x 128 k (stride 136)
    ushort* Bs = sbuf + 32 * 136;   // 64 rows x 128 k (stride 136)

    const int n0 = blockIdx.x * 64;
    const int m0 = blockIdx.y * 32;

    const int tid = threadIdx.x;
    const int arow = tid >> 3;          // 0..31
    const int acol = (tid & 7) * 16;    // 0..112
    const int brow = tid >> 2;          // 0..63
    const int bcol = (tid & 3) * 32;    // 0,32,64,96

    const ushort* Ap = &Ab[(size_t)(m0 + arow) * E_ + acol];
    const float*  Wp = &Wo[(size_t)(n0 + brow) * E_ + bcol];

    f32x4 acc[2];
    acc[0] = (f32x4){0.f, 0.f, 0.f, 0.f};
    acc[1] = (f32x4){0.f, 0.f, 0.f, 0.f};

    uint4  ha0 = *(const uint4*)&Ap[0];
    uint4  ha1 = *(const uint4*)&Ap[8];
    float4 f0 = *(const float4*)&Wp[0];
    float4 f1 = *(const float4*)&Wp[4];
    float4 f2 = *(const float4*)&Wp[8];
    float4 f3 = *(const float4*)&Wp[12];
    float4 f4 = *(const float4*)&Wp[16];
    float4 f5 = *(const float4*)&Wp[20];
    float4 f6 = *(const float4*)&Wp[24];
    float4 f7 = *(const float4*)&Wp[28];

    const int l  = tid & 63;
    const int w  = tid >> 6;
    const int wm = w & 1;          // 16-row m half
    const int wn = w >> 1;         // 32-col n half
    const int lq = l >> 4;
    const int ln = l & 15;

    for (int it = 0; it < 4; ++it) {
        __syncthreads();
        *(uint4*)&As[arow * 136 + acol]     = ha0;
        *(uint4*)&As[arow * 136 + acol + 8] = ha1;
        *(uint4*)&Bs[brow * 136 + bcol]      = make_uint4(cvtpk(f0.x, f0.y), cvtpk(f0.z, f0.w),
                                                          cvtpk(f1.x, f1.y), cvtpk(f1.z, f1.w));
        *(uint4*)&Bs[brow * 136 + bcol + 8]  = make_uint4(cvtpk(f2.x, f2.y), cvtpk(f2.z, f2.w),
                                                          cvtpk(f3.x, f3.y), cvtpk(f3.z, f3.w));
        *(uint4*)&Bs[brow * 136 + bcol + 16] = make_uint4(cvtpk(f4.x, f4.y), cvtpk(f4.z, f4.w),
                                                          cvtpk(f5.x, f5.y), cvtpk(f5.z, f5.w));
        *(uint4*)&Bs[brow * 136 + bcol + 24] = make_uint4(cvtpk(f6.x, f6.y), cvtpk(f6.z, f6.w),
                                                          cvtpk(f7.x, f7.y), cvtpk(f7.z, f7.w));
        __syncthreads();
        if (it < 3) {
            Ap += 128; Wp += 128;
            ha0 = *(const uint4*)&Ap[0];
            ha1 = *(const uint4*)&Ap[8];
            f0 = *(const float4*)&Wp[0];
            f1 = *(const float4*)&Wp[4];
            f2 = *(const float4*)&Wp[8];
            f3 = *(const float4*)&Wp[12];
            f4 = *(const float4*)&Wp[16];
            f5 = *(const float4*)&Wp[20];
            f6 = *(const float4*)&Wp[24];
            f7 = *(const float4*)&Wp[28];
        }
#pragma unroll
        for (int kb = 0; kb < 4; ++kb) {
            bf16x8 af  = *(const bf16x8*)&As[(wm * 16 + ln) * 136 + kb * 32 + lq * 8];
            bf16x8 bv0 = *(const bf16x8*)&Bs[(wn * 32 + ln) * 136 + kb * 32 + lq * 8];
            bf16x8 bv1 = *(const bf16x8*)&Bs[(wn * 32 + 16 + ln) * 136 + kb * 32 + lq * 8];
            acc[0] = __builtin_amdgcn_mfma_f32_16x16x32_bf16(af, bv0, acc[0], 0, 0, 0);
            acc[1] = __builtin_amdgcn_mfma_f32_16x16x32_bf16(af, bv1, acc[1], 0, 0, 0);
        }
    }

    const float bo0 = bo[n0 + wn * 32 + ln];
    const float bo1 = bo[n0 + wn * 32 + 16 + ln];

    __syncthreads();
    float* Lf = (float*)sbuf;       // 32 x 68 f32 = 8704 B (aliases As)
#pragma unroll
    for (int j = 0; j < 2; ++j) {
        const float bb = j ? bo1 : bo0;
        const f32x4 a = acc[j];
#pragma unroll
        for (int r = 0; r < 4; ++r)
            Lf[(wm * 16 + lq * 4 + r) * 68 + wn * 32 + j * 16 + ln] = a[r] + bb;
    }
    __syncthreads();

    {
        const int orow = tid >> 3;          // 0..31
        const int oc8  = (tid & 7) * 8;     // 0..56
        float* dp = &dst[(size_t)(m0 + orow) * E_ + n0 + oc8];
        float4 v0 = *(const float4*)&Lf[orow * 68 + oc8];
        float4 v1 = *(const float4*)&Lf[orow * 68 + oc8 + 4];
        *(float4*)&dp[0] = v0;
        *(float4*)&dp[4] = v1;
    }
}

// ---------------------------------------------------------------------------
extern "C" void kernel_launch(void* const* d_in, const int* in_sizes, int n_in,
                              void* d_out, int out_size, void* d_ws, size_t ws_size,
                              hipStream_t stream)
{
    const float* query = (const float*)d_in[0];
    const int*   oc    = (const int*)d_in[1];
    const int*   em    = (const int*)d_in[2];
    const int*   kpm   = (const int*)d_in[3];
    const float* law   = (const float*)d_in[4];
    const float* Wq    = (const float*)d_in[5];
    const float* bq    = (const float*)d_in[6];
    const float* Wk    = (const float*)d_in[7];
    const float* Wv    = (const float*)d_in[8];
    const float* bv    = (const float*)d_in[9];
    const float* Wo    = (const float*)d_in[10];
    const float* bo    = (const float*)d_in[11];
    float* out = (float*)d_out;

    ushort* Ab = (ushort*)d_ws;     // row-major [M][E] bf16

    qkv_attn_kernel<<<B_ * H_, 1024, 0, stream>>>(query, Wq, Wk, Wv, bq, bv,
                                                  law, kpm, em, oc, Ab);

    dim3 go(E_ / 64, M_ / 32, 1);
    out_gemm<<<go, 256, 0, stream>>>(Ab, Wo, bo, out);
}